// Round 6
// baseline (247.264 us; speedup 1.0000x reference)
//
#include <hip/hip_runtime.h>
#include <hip/hip_bf16.h>

// KAN layer as augmented GEMM:
//   Af[b, c*1024+i] = c==0 ? silu(x[b,i]) : basis_{c-1}(x[b,i])   (bf16)
//   Wf[o, c*1024+i] = c==0 ? base_w[o,i]  : spline_w[o,i,c-1]     (bf16)
//   out = Af @ Wf^T  (fp32 accum via MFMA)
//
// GEMM: 256x128 tile, BK=32, 256 threads / 4 waves, wave owns a SPLIT
// 128x64 tile (rows {wm*64..}U{128+wm*64..}, cols {wn*32..}U{64+wn*32..})
// -> 42.7 FLOP/LDS-byte and uniform per-phase half-tile needs.
// LDS dbuf 48KB + ~190 regs -> 2 async blocks/CU (cross-block overlap).
// 4 phases/tile {A0B0, B1, A1, -}, counted vmcnt(3/4/3), 3 barriers/tile,
// stage order A0,B0,B1,A1 (1-2 gloads/phase). Tail tile peeled with
// vmcnt(3/2/0). Split-K=2 (grid 512) + reduce. T1 bijective XCD swizzle.
#define B_DIM 8192
#define I_DIM 1024
#define O_DIM 1024
#define K_DIM 9216   // 9 * 1024

#define BM 256
#define BN 128
#define BK 32

typedef unsigned short ushort_t;
typedef __attribute__((ext_vector_type(8))) short short8;
typedef __attribute__((ext_vector_type(4))) float f32x4;

#define MFMA(a, b, c) __builtin_amdgcn_mfma_f32_16x16x32_bf16((a), (b), (c), 0, 0, 0)

__device__ __forceinline__ ushort_t f2bf(float f) {
    unsigned u = __float_as_uint(f);
    unsigned r = 0x7fffu + ((u >> 16) & 1u);
    return (ushort_t)((u + r) >> 16);
}

__device__ __forceinline__ void llds16(const ushort_t* g, ushort_t* l) {
    __builtin_amdgcn_global_load_lds(
        (const __attribute__((address_space(1))) unsigned int*)g,
        (__attribute__((address_space(3))) unsigned int*)l,
        16, 0, 0);
}

// ---------------- expansion: weights ----------------
__global__ __launch_bounds__(256) void expand_w_kernel(
        const float* __restrict__ bw, const float* __restrict__ sw,
        ushort_t* __restrict__ Wf) {
    int idx = blockIdx.x * 256 + threadIdx.x;   // one thread: (o, 2 consecutive i)
    int o = idx >> 9;
    int i = (idx & 511) << 1;
    ushort_t* out = Wf + (size_t)o * K_DIM + i;
    const float* bp = bw + ((size_t)o << 10) + i;
    *(unsigned*)out = (unsigned)f2bf(bp[0]) | ((unsigned)f2bf(bp[1]) << 16);
    const float* sp = sw + (((size_t)o << 10) + i) * 8;   // 16 contiguous floats
    float v[16];
    #pragma unroll
    for (int n = 0; n < 16; ++n) v[n] = sp[n];
    #pragma unroll
    for (int n = 0; n < 8; ++n)
        *(unsigned*)(out + (size_t)(n + 1) * 1024) =
            (unsigned)f2bf(v[n]) | ((unsigned)f2bf(v[8 + n]) << 16);
}

// ---------------- expansion: activations ----------------
__global__ __launch_bounds__(256) void expand_a_kernel(
        const float* __restrict__ x, ushort_t* __restrict__ Af) {
    int idx = blockIdx.x * 256 + threadIdx.x;   // one thread: (b, 2 consecutive i)
    int b = idx >> 9;
    int i = (idx & 511) << 1;
    const float* xp = x + ((size_t)b << 10) + i;
    float x0 = xp[0], x1 = xp[1];
    ushort_t* out = Af + (size_t)b * K_DIM + i;
    float s0 = x0 / (1.0f + __expf(-x0));
    float s1 = x1 / (1.0f + __expf(-x1));
    *(unsigned*)out = (unsigned)f2bf(s0) | ((unsigned)f2bf(s1) << 16);
    // quadratic B-spline basis, uniform knots -9..9 step 1.8
    float t0 = (x0 + 9.0f) * (1.0f / 1.8f);
    float t1 = (x1 + 9.0f) * (1.0f / 1.8f);
    float fj0 = floorf(t0), fj1 = floorf(t1);
    int j0 = (int)fj0, j1 = (int)fj1;
    float u0 = t0 - fj0, u1 = t1 - fj1;
    float p0 = 0.5f * (1.f - u0) * (1.f - u0);
    float p1 = 0.5f * (-2.f * u0 * u0 + 2.f * u0 + 1.f);
    float p2 = 0.5f * u0 * u0;
    float q0 = 0.5f * (1.f - u1) * (1.f - u1);
    float q1 = 0.5f * (-2.f * u1 * u1 + 2.f * u1 + 1.f);
    float q2 = 0.5f * u1 * u1;
    #pragma unroll
    for (int n = 0; n < 8; ++n) {
        float v0 = (n == j0 - 2) ? p0 : (n == j0 - 1) ? p1 : (n == j0) ? p2 : 0.f;
        float v1 = (n == j1 - 2) ? q0 : (n == j1 - 1) ? q1 : (n == j1) ? q2 : 0.f;
        *(unsigned*)(out + (size_t)(n + 1) * 1024) =
            (unsigned)f2bf(v0) | ((unsigned)f2bf(v1) << 16);
    }
}

// ---------------- GEMM: out[M=8192, N=1024] = Af[M,K] * Wf[N,K]^T ----------------
// grid = 256 * nsplit; wgid = split*256 + bm*8 + bn.
__global__ __launch_bounds__(256, 2) void gemm_bt(
        const ushort_t* __restrict__ Af,
        const ushort_t* __restrict__ Wf,
        float* __restrict__ out, float* __restrict__ part1,
        int kTiles, int nwg) {
    __shared__ __align__(16) ushort_t As[2][BM * BK];   // 2 x 16 KB
    __shared__ __align__(16) ushort_t Bs[2][BN * BK];   // 2 x  8 KB

    const int tid = threadIdx.x;

    // T1: bijective XCD swizzle (nwg divisible by 8)
    const int orig = blockIdx.x;
    const int wgid = (orig & 7) * (nwg >> 3) + (orig >> 3);
    const int split = wgid >> 8;            // 256 blocks per split
    const int bm = (wgid & 255) >> 3;       // 0..31
    const int bn = wgid & 7;                // 0..7
    const int mBase = bm * BM, nBase = bn * BN;
    const size_t kOff = (size_t)split * kTiles * BK;

    const int lane = tid & 63;
    const int w = tid >> 6;                 // 4 waves
    const int wm = w >> 1, wn = w & 1;      // 2M x 2N
    const int fr = lane & 15;
    const int kg = lane >> 4;               // k-group 0..3 (8-elem slots)

    // staging: 256 threads x 16B = 4KB/round = 64 rows of 64B.
    // swizzle: 16B slot ^= (row&3); source pre-swizzled, LDS dest linear.
    const int srow = tid >> 2;                                  // 0..63
    const int scolE = (((tid & 3) ^ (srow & 3)) << 3);          // pre-swizzled col (elems)
    const int sdst = (tid & ~63) * 8;                           // wave-uniform elem offset

    auto stageA = [&](int t, int buf, int h, int r) {           // half h (128 rows), round r (64 rows)
        const ushort_t* g = Af + (size_t)(mBase + h * 128 + r * 64 + srow) * K_DIM
                               + kOff + (size_t)t * BK + scolE;
        llds16(g, &As[buf][(h * 2 + r) * 2048 + sdst]);
    };
    auto stageB = [&](int t, int buf, int h) {                  // half h (64 rows)
        const ushort_t* g = Wf + (size_t)(nBase + h * 64 + srow) * K_DIM
                               + kOff + (size_t)t * BK + scolE;
        llds16(g, &Bs[buf][h * 2048 + sdst]);
    };

    // read offsets (swizzled to match staging); row&3 == fr&3 everywhere
    const int swz = ((kg ^ (fr & 3)) << 3);
    int offA[8], offB[4];
    #pragma unroll
    for (int mi = 0; mi < 8; ++mi) {
        int row = (mi < 4 ? wm * 64 + mi * 16 : 128 + wm * 64 + (mi - 4) * 16) + fr;
        offA[mi] = row * BK + swz;
    }
    #pragma unroll
    for (int ni = 0; ni < 4; ++ni) {
        int row = (ni < 2 ? wn * 32 + ni * 16 : 64 + wn * 32 + (ni - 2) * 16) + fr;
        offB[ni] = row * BK + swz;
    }

    f32x4 acc[8][4];
    #pragma unroll
    for (int mi = 0; mi < 8; ++mi)
        #pragma unroll
        for (int ni = 0; ni < 4; ++ni) acc[mi][ni] = (f32x4){0.f, 0.f, 0.f, 0.f};

    // prologue: tile 0 in FIFO order A0,B0,B1,A1 (6 loads/thread)
    stageA(0, 0, 0, 0); stageA(0, 0, 0, 1);
    stageB(0, 0, 0);
    stageB(0, 0, 1);
    stageA(0, 0, 1, 0); stageA(0, 0, 1, 1);

    // per-tile body: phases {p0: A0+B0, p1: B1, p2: A1, p3: regs only}
#define TILE_BODY(VM0, VM1, VM2, DOSTAGE)                                        \
    {                                                                             \
        const ushort_t* A_ = As[cur];                                             \
        const ushort_t* B_ = Bs[cur];                                             \
        short8 a0, a1, a2, a3, b0, b1, b2, b3;                                    \
        /* ---- p0: needs A0(t), B0(t) ---- */                                    \
        asm volatile("s_waitcnt vmcnt(" VM0 ")" ::: "memory");                    \
        __builtin_amdgcn_s_barrier();                                             \
        if (DOSTAGE) { stageA(t + 1, nb, 0, 0); stageA(t + 1, nb, 0, 1); }        \
        a0 = *(const short8*)&A_[offA[0]]; a1 = *(const short8*)&A_[offA[1]];     \
        a2 = *(const short8*)&A_[offA[2]]; a3 = *(const short8*)&A_[offA[3]];     \
        b0 = *(const short8*)&B_[offB[0]]; b1 = *(const short8*)&B_[offB[1]];     \
        asm volatile("s_waitcnt lgkmcnt(0)" ::: "memory");                        \
        __builtin_amdgcn_sched_barrier(0);                                        \
        __builtin_amdgcn_s_setprio(1);                                            \
        acc[0][0] = MFMA(a0, b0, acc[0][0]); acc[0][1] = MFMA(a0, b1, acc[0][1]); \
        acc[1][0] = MFMA(a1, b0, acc[1][0]); acc[1][1] = MFMA(a1, b1, acc[1][1]); \
        acc[2][0] = MFMA(a2, b0, acc[2][0]); acc[2][1] = MFMA(a2, b1, acc[2][1]); \
        acc[3][0] = MFMA(a3, b0, acc[3][0]); acc[3][1] = MFMA(a3, b1, acc[3][1]); \
        __builtin_amdgcn_s_setprio(0);                                            \
        /* ---- p1: needs B1(t) ---- */                                           \
        asm volatile("s_waitcnt vmcnt(" VM1 ")" ::: "memory");                    \
        __builtin_amdgcn_s_barrier();                                             \
        if (DOSTAGE) { stageB(t + 1, nb, 0); }                                    \
        b2 = *(const short8*)&B_[offB[2]]; b3 = *(const short8*)&B_[offB[3]];     \
        asm volatile("s_waitcnt lgkmcnt(0)" ::: "memory");                        \
        __builtin_amdgcn_sched_barrier(0);                                        \
        __builtin_amdgcn_s_setprio(1);                                            \
        acc[0][2] = MFMA(a0, b2, acc[0][2]); acc[0][3] = MFMA(a0, b3, acc[0][3]); \
        acc[1][2] = MFMA(a1, b2, acc[1][2]); acc[1][3] = MFMA(a1, b3, acc[1][3]); \
        acc[2][2] = MFMA(a2, b2, acc[2][2]); acc[2][3] = MFMA(a2, b3, acc[2][3]); \
        acc[3][2] = MFMA(a3, b2, acc[3][2]); acc[3][3] = MFMA(a3, b3, acc[3][3]); \
        __builtin_amdgcn_s_setprio(0);                                            \
        /* ---- p2: needs A1(t) ---- */                                           \
        asm volatile("s_waitcnt vmcnt(" VM2 ")" ::: "memory");                    \
        __builtin_amdgcn_s_barrier();                                             \
        if (DOSTAGE) { stageB(t + 1, nb, 1); }                                    \
        a0 = *(const short8*)&A_[offA[4]]; a1 = *(const short8*)&A_[offA[5]];     \
        a2 = *(const short8*)&A_[offA[6]]; a3 = *(const short8*)&A_[offA[7]];     \
        asm volatile("s_waitcnt lgkmcnt(0)" ::: "memory");                        \
        __builtin_amdgcn_sched_barrier(0);                                        \
        __builtin_amdgcn_s_setprio(1);                                            \
        acc[4][0] = MFMA(a0, b0, acc[4][0]); acc[4][1] = MFMA(a0, b1, acc[4][1]); \
        acc[5][0] = MFMA(a1, b0, acc[5][0]); acc[5][1] = MFMA(a1, b1, acc[5][1]); \
        acc[6][0] = MFMA(a2, b0, acc[6][0]); acc[6][1] = MFMA(a2, b1, acc[6][1]); \
        acc[7][0] = MFMA(a3, b0, acc[7][0]); acc[7][1] = MFMA(a3, b1, acc[7][1]); \
        __builtin_amdgcn_s_setprio(0);                                            \
        /* ---- p3: registers only, no barrier ---- */                            \
        if (DOSTAGE) { stageA(t + 1, nb, 1, 0); stageA(t + 1, nb, 1, 1); }        \
        __builtin_amdgcn_s_setprio(1);                                            \
        acc[4][2] = MFMA(a0, b2, acc[4][2]); acc[4][3] = MFMA(a0, b3, acc[4][3]); \
        acc[5][2] = MFMA(a1, b2, acc[5][2]); acc[5][3] = MFMA(a1, b3, acc[5][3]); \
        acc[6][2] = MFMA(a2, b2, acc[6][2]); acc[6][3] = MFMA(a2, b3, acc[6][3]); \
        acc[7][2] = MFMA(a3, b2, acc[7][2]); acc[7][3] = MFMA(a3, b3, acc[7][3]); \
        __builtin_amdgcn_s_setprio(0);                                            \
    }

    for (int t = 0; t < kTiles - 1; ++t) {
        const int cur = t & 1, nb = cur ^ 1;
        TILE_BODY("3", "4", "3", true)
    }
    {   // tail tile: nothing newer in flight -> drain progressively
        const int t = kTiles - 1;
        const int cur = t & 1, nb = cur ^ 1;
        (void)nb;
        TILE_BODY("3", "2", "0", false)
    }
#undef TILE_BODY

    // epilogue: C/D layout col=lane&15, row=(lane>>4)*4+r
    float* obase = split ? part1 : out;
    const int orow = (lane >> 4) * 4;
    const int ocol = lane & 15;
    #pragma unroll
    for (int mi = 0; mi < 8; ++mi) {
        int rbase = mBase + (mi < 4 ? wm * 64 + mi * 16
                                    : 128 + wm * 64 + (mi - 4) * 16) + orow;
        #pragma unroll
        for (int ni = 0; ni < 4; ++ni) {
            int c = nBase + (ni < 2 ? wn * 32 + ni * 16
                                    : 64 + wn * 32 + (ni - 2) * 16) + ocol;
            size_t base = (size_t)rbase * O_DIM + c;
            #pragma unroll
            for (int r = 0; r < 4; ++r)
                obase[base + (size_t)r * O_DIM] = acc[mi][ni][r];
        }
    }
}

// ---------------- reduce: out += part1 (float4) ----------------
__global__ __launch_bounds__(256) void reduce_kernel(
        float* __restrict__ out, const float* __restrict__ p1) {
    int i = blockIdx.x * 256 + threadIdx.x;   // float4 index, 2M total
    f32x4 a = ((const f32x4*)out)[i];
    f32x4 b = ((const f32x4*)p1)[i];
    ((f32x4*)out)[i] = a + b;
}

extern "C" void kernel_launch(void* const* d_in, const int* in_sizes, int n_in,
                              void* d_out, int out_size, void* d_ws, size_t ws_size,
                              hipStream_t stream) {
    const float* x  = (const float*)d_in[0];
    const float* bw = (const float*)d_in[1];
    const float* sw = (const float*)d_in[2];
    float* out = (float*)d_out;

    // ws layout: Wf [1024 x 9216] bf16 (18.9 MB), Af [8192 x 9216] bf16 (151 MB),
    // part1 [8192 x 1024] fp32 (33.6 MB)
    const size_t nW = (size_t)O_DIM * K_DIM;
    const size_t nA = (size_t)B_DIM * K_DIM;
    ushort_t* Wf = (ushort_t*)d_ws;
    ushort_t* Af = Wf + nW;
    float* part1 = (float*)(Af + nA);
    const size_t need = (nW + nA) * 2 + (size_t)B_DIM * O_DIM * 4;

    const int nsplit = (ws_size >= need) ? 2 : 1;   // ws_size constant -> deterministic
    const int kTiles = (K_DIM / BK) / nsplit;       // 144 or 288
    const int nwg = 256 * nsplit;

    expand_w_kernel<<<(O_DIM * I_DIM / 2) / 256, 256, 0, stream>>>(bw, sw, Wf);
    expand_a_kernel<<<(B_DIM * I_DIM / 2) / 256, 256, 0, stream>>>(x, Af);
    gemm_bt<<<nwg, 256, 0, stream>>>(Af, Wf, out, part1, kTiles, nwg);
    if (nsplit == 2)
        reduce_kernel<<<(B_DIM * O_DIM / 4) / 256, 256, 0, stream>>>(out, part1);
}

// Round 8
// 212.892 us; speedup vs baseline: 1.1615x; 1.1615x over previous
//
#include <hip/hip_runtime.h>
#include <hip/hip_bf16.h>

// KAN layer as augmented GEMM:
//   Af[b, c*1024+i] = c==0 ? silu(x[b,i]) : basis_{c-1}(x[b,i])   (bf16)
//   Wf[o, c*1024+i] = c==0 ? base_w[o,i]  : spline_w[o,i,c-1]     (bf16)
//   out = Af @ Wf^T  (fp32 accum via MFMA)
//
// GEMM: 256x256 tile, BK=64, 8 waves 2Mx4N (128x64/wave -> 42.7 FLOP per
// LDS-read-byte), A ring-3 + B dbuf = 160KiB. K-tile body = 4 barrier-
// delimited regions of EXACTLY 16 MFMA each (round-4/m201 rhythm):
// r0{12 ds_reads}, r1{stage B(t+1), 4 reads}, r2{8 reads}, r3{stage
// A(t+2)}. Counted vmcnt(4) at top only. (row&7) 16B-slot XOR swizzle
// (0-conflict, BK=64 only!). T5 setprio, T1 bijective XCD swizzle,
// split-K=2 (grid 256) + fp32 reduce.
#define B_DIM 8192
#define I_DIM 1024
#define O_DIM 1024
#define K_DIM 9216   // 9 * 1024

#define BM 256
#define BN 256
#define BK 64

typedef unsigned short ushort_t;
typedef __attribute__((ext_vector_type(8))) short short8;
typedef __attribute__((ext_vector_type(4))) float f32x4;

#define MFMA(a, b, c) __builtin_amdgcn_mfma_f32_16x16x32_bf16((a), (b), (c), 0, 0, 0)

__device__ __forceinline__ ushort_t f2bf(float f) {
    unsigned u = __float_as_uint(f);
    unsigned r = 0x7fffu + ((u >> 16) & 1u);
    return (ushort_t)((u + r) >> 16);
}

__device__ __forceinline__ void llds16(const ushort_t* g, ushort_t* l) {
    __builtin_amdgcn_global_load_lds(
        (const __attribute__((address_space(1))) unsigned int*)g,
        (__attribute__((address_space(3))) unsigned int*)l,
        16, 0, 0);
}

// ---------------- expansion: weights ----------------
__global__ __launch_bounds__(256) void expand_w_kernel(
        const float* __restrict__ bw, const float* __restrict__ sw,
        ushort_t* __restrict__ Wf) {
    int idx = blockIdx.x * 256 + threadIdx.x;   // one thread: (o, 2 consecutive i)
    int o = idx >> 9;
    int i = (idx & 511) << 1;
    ushort_t* out = Wf + (size_t)o * K_DIM + i;
    const float* bp = bw + ((size_t)o << 10) + i;
    *(unsigned*)out = (unsigned)f2bf(bp[0]) | ((unsigned)f2bf(bp[1]) << 16);
    const float* sp = sw + (((size_t)o << 10) + i) * 8;   // 16 contiguous floats
    float v[16];
    #pragma unroll
    for (int n = 0; n < 16; ++n) v[n] = sp[n];
    #pragma unroll
    for (int n = 0; n < 8; ++n)
        *(unsigned*)(out + (size_t)(n + 1) * 1024) =
            (unsigned)f2bf(v[n]) | ((unsigned)f2bf(v[8 + n]) << 16);
}

// ---------------- expansion: activations ----------------
__global__ __launch_bounds__(256) void expand_a_kernel(
        const float* __restrict__ x, ushort_t* __restrict__ Af) {
    int idx = blockIdx.x * 256 + threadIdx.x;   // one thread: (b, 2 consecutive i)
    int b = idx >> 9;
    int i = (idx & 511) << 1;
    const float* xp = x + ((size_t)b << 10) + i;
    float x0 = xp[0], x1 = xp[1];
    ushort_t* out = Af + (size_t)b * K_DIM + i;
    float s0 = x0 / (1.0f + __expf(-x0));
    float s1 = x1 / (1.0f + __expf(-x1));
    *(unsigned*)out = (unsigned)f2bf(s0) | ((unsigned)f2bf(s1) << 16);
    // quadratic B-spline basis, uniform knots -9..9 step 1.8
    float t0 = (x0 + 9.0f) * (1.0f / 1.8f);
    float t1 = (x1 + 9.0f) * (1.0f / 1.8f);
    float fj0 = floorf(t0), fj1 = floorf(t1);
    int j0 = (int)fj0, j1 = (int)fj1;
    float u0 = t0 - fj0, u1 = t1 - fj1;
    float p0 = 0.5f * (1.f - u0) * (1.f - u0);
    float p1 = 0.5f * (-2.f * u0 * u0 + 2.f * u0 + 1.f);
    float p2 = 0.5f * u0 * u0;
    float q0 = 0.5f * (1.f - u1) * (1.f - u1);
    float q1 = 0.5f * (-2.f * u1 * u1 + 2.f * u1 + 1.f);
    float q2 = 0.5f * u1 * u1;
    #pragma unroll
    for (int n = 0; n < 8; ++n) {
        float v0 = (n == j0 - 2) ? p0 : (n == j0 - 1) ? p1 : (n == j0) ? p2 : 0.f;
        float v1 = (n == j1 - 2) ? q0 : (n == j1 - 1) ? q1 : (n == j1) ? q2 : 0.f;
        *(unsigned*)(out + (size_t)(n + 1) * 1024) =
            (unsigned)f2bf(v0) | ((unsigned)f2bf(v1) << 16);
    }
}

// ---------------- GEMM: out[M=8192, N=1024] = Af[M,K] * Wf[N,K]^T ----------------
// grid = 128 * nsplit; wgid = split*128 + bm*4 + bn.
__global__ __launch_bounds__(512, 1) void gemm_bt(
        const ushort_t* __restrict__ Af,
        const ushort_t* __restrict__ Wf,
        float* __restrict__ out, float* __restrict__ part1,
        int kTiles) {
    // A ring-3 (96KB, prefetch distance 2) + B dbuf (64KB, distance 1) = 160KiB
    __shared__ __align__(16) ushort_t As[3][BM * BK];
    __shared__ __align__(16) ushort_t Bs[2][BN * BK];

    const int tid = threadIdx.x;

    // T1: bijective XCD swizzle (nwg divisible by 8)
    const int nwg = gridDim.x;
    const int orig = blockIdx.x;
    const int wgid = (orig & 7) * (nwg >> 3) + (orig >> 3);
    const int split = wgid >> 7;            // 128 blocks per split
    const int bm = (wgid & 127) >> 2;       // 0..31
    const int bn = wgid & 3;                // 0..3
    const int mBase = bm * BM, nBase = bn * BN;
    const size_t kOff = (size_t)split * kTiles * BK;

    const int lane = tid & 63;
    const int w = tid >> 6;                 // 8 waves: 2M x 4N -> 128x64 per wave
    const int wr = (w >> 2) * 128;
    const int wc = (w & 3) * 64;
    const int fr = lane & 15;
    const int kg = lane >> 4;               // k-group 0..3

    // staging: 512 threads x 16B = 8KB per round = 64 rows of 128B; 4 rounds each.
    // T2 swizzle: 16B slot ^= (row&7); source pre-swizzled, LDS dest linear.
    const int srow = tid >> 3;                                  // 0..63
    const int scolE = (((tid & 7) ^ (srow & 7)) << 3);          // pre-swizzled source col
    const int sdst = (tid & ~63) * 8;                           // wave-uniform elem offset

    auto stageA = [&](int t, int buf, int rnd) {
        const ushort_t* g = Af + (size_t)(mBase + rnd * 64 + srow) * K_DIM
                               + kOff + (size_t)t * BK + scolE;
        llds16(g, &As[buf][rnd * 4096 + sdst]);
    };
    auto stageB = [&](int t, int buf, int rnd) {
        const ushort_t* g = Wf + (size_t)(nBase + rnd * 64 + srow) * K_DIM
                               + kOff + (size_t)t * BK + scolE;
        llds16(g, &Bs[buf][rnd * 4096 + sdst]);
    };

    // read-side swizzled 16B-slot offsets: row&7 == fr&7 (wr, wc, 16*m mult of 16)
    const int swz0 = ((kg ^ (fr & 7)) << 3);          // kk = 0
    const int swz1 = (((4 + kg) ^ (fr & 7)) << 3);    // kk = 1

    f32x4 acc[8][4];
    #pragma unroll
    for (int m = 0; m < 8; ++m)
        #pragma unroll
        for (int n = 0; n < 4; ++n) acc[m][n] = (f32x4){0.f, 0.f, 0.f, 0.f};

    // K-tile body: 4 regions x 16 MFMA, barrier-delimited (round-4 rhythm).
    auto tile_body = [&](int t, int ca, int pa, bool doB, bool doA) {
        const ushort_t* A_ = As[ca];
        const ushort_t* B_ = Bs[t & 1];
        short8 a[4][2], b0[2][2], b1[2][2];

        // ---- r0: reads a0-3 + b0 (12 ds_read_b128); MFMA acc[0..3][0..1] ----
        #pragma unroll
        for (int m = 0; m < 4; ++m) {
            int arow = (wr + m * 16 + fr) * BK;
            a[m][0] = *(const short8*)&A_[arow + swz0];
            a[m][1] = *(const short8*)&A_[arow + swz1];
        }
        #pragma unroll
        for (int n = 0; n < 2; ++n) {
            int brow = (wc + n * 16 + fr) * BK;
            b0[n][0] = *(const short8*)&B_[brow + swz0];
            b0[n][1] = *(const short8*)&B_[brow + swz1];
        }
        asm volatile("s_waitcnt lgkmcnt(0)" ::: "memory");
        __builtin_amdgcn_sched_barrier(0);
        __builtin_amdgcn_s_setprio(1);
        #pragma unroll
        for (int m = 0; m < 4; ++m)
            #pragma unroll
            for (int n = 0; n < 2; ++n) {
                acc[m][n] = MFMA(a[m][0], b0[n][0], acc[m][n]);
                acc[m][n] = MFMA(a[m][1], b0[n][1], acc[m][n]);
            }
        __builtin_amdgcn_s_setprio(0);
        __builtin_amdgcn_s_barrier();

        // ---- r1: stage B(t+1); read b1 (4 reads); MFMA acc[0..3][2..3] ----
        if (doB) {
            stageB(t + 1, (t + 1) & 1, 0); stageB(t + 1, (t + 1) & 1, 1);
            stageB(t + 1, (t + 1) & 1, 2); stageB(t + 1, (t + 1) & 1, 3);
        }
        #pragma unroll
        for (int n = 0; n < 2; ++n) {
            int brow = (wc + (2 + n) * 16 + fr) * BK;
            b1[n][0] = *(const short8*)&B_[brow + swz0];
            b1[n][1] = *(const short8*)&B_[brow + swz1];
        }
        asm volatile("s_waitcnt lgkmcnt(0)" ::: "memory");
        __builtin_amdgcn_sched_barrier(0);
        __builtin_amdgcn_s_setprio(1);
        #pragma unroll
        for (int m = 0; m < 4; ++m)
            #pragma unroll
            for (int n = 0; n < 2; ++n) {
                acc[m][2 + n] = MFMA(a[m][0], b1[n][0], acc[m][2 + n]);
                acc[m][2 + n] = MFMA(a[m][1], b1[n][1], acc[m][2 + n]);
            }
        __builtin_amdgcn_s_setprio(0);
        __builtin_amdgcn_s_barrier();

        // ---- r2: read a4-7 (8 reads); MFMA acc[4..7][0..1] ----
        #pragma unroll
        for (int m = 0; m < 4; ++m) {
            int arow = (wr + (4 + m) * 16 + fr) * BK;
            a[m][0] = *(const short8*)&A_[arow + swz0];
            a[m][1] = *(const short8*)&A_[arow + swz1];
        }
        asm volatile("s_waitcnt lgkmcnt(0)" ::: "memory");
        __builtin_amdgcn_sched_barrier(0);
        __builtin_amdgcn_s_setprio(1);
        #pragma unroll
        for (int m = 0; m < 4; ++m)
            #pragma unroll
            for (int n = 0; n < 2; ++n) {
                acc[4 + m][n] = MFMA(a[m][0], b0[n][0], acc[4 + m][n]);
                acc[4 + m][n] = MFMA(a[m][1], b0[n][1], acc[4 + m][n]);
            }
        __builtin_amdgcn_s_setprio(0);
        __builtin_amdgcn_s_barrier();

        // ---- r3: stage A(t+2); MFMA acc[4..7][2..3] (no reads) ----
        if (doA) {
            stageA(t + 2, pa, 0); stageA(t + 2, pa, 1);
            stageA(t + 2, pa, 2); stageA(t + 2, pa, 3);
        }
        __builtin_amdgcn_s_setprio(1);
        #pragma unroll
        for (int m = 0; m < 4; ++m)
            #pragma unroll
            for (int n = 0; n < 2; ++n) {
                acc[4 + m][2 + n] = MFMA(a[m][0], b1[n][0], acc[4 + m][2 + n]);
                acc[4 + m][2 + n] = MFMA(a[m][1], b1[n][1], acc[4 + m][2 + n]);
            }
        __builtin_amdgcn_s_setprio(0);
    };

    // prologue FIFO order: B(0), A(0), A(1)  (vmcnt(4) at t=0 drains B0,A0)
    stageB(0, 0, 0); stageB(0, 0, 1); stageB(0, 0, 2); stageB(0, 0, 3);
    stageA(0, 0, 0); stageA(0, 0, 1); stageA(0, 0, 2); stageA(0, 0, 3);
    stageA(1, 1, 0); stageA(1, 1, 1); stageA(1, 1, 2); stageA(1, 1, 3);

    int ca = 0;   // A ring slot holding tile t
    for (int t = 0; t < kTiles - 1; ++t) {
        // drain through B(t),A(t); tolerate newest 4 (= A(t+1))
        asm volatile("s_waitcnt vmcnt(4)" ::: "memory");
        __builtin_amdgcn_s_barrier();
        const int pa = (ca >= 1) ? ca - 1 : 2;   // (ca+2)%3
        tile_body(t, ca, pa, true, t + 2 < kTiles);
        ca = (ca + 1 == 3) ? 0 : ca + 1;
    }
    {   // tail tile: drain everything
        const int t = kTiles - 1;
        asm volatile("s_waitcnt vmcnt(0)" ::: "memory");
        __builtin_amdgcn_s_barrier();
        tile_body(t, ca, 0, false, false);
    }

    // epilogue: C/D layout col=lane&15, row=(lane>>4)*4+r
    float* obase = split ? part1 : out;
    const int orow = (lane >> 4) * 4;
    const int ocol = lane & 15;
    #pragma unroll
    for (int m = 0; m < 8; ++m)
        #pragma unroll
        for (int n = 0; n < 4; ++n) {
            size_t base = (size_t)(mBase + wr + m * 16 + orow) * O_DIM
                        + (nBase + wc + n * 16 + ocol);
            #pragma unroll
            for (int r = 0; r < 4; ++r)
                obase[base + (size_t)r * O_DIM] = acc[m][n][r];
        }
}

// ---------------- reduce: out += part1 (float4) ----------------
__global__ __launch_bounds__(256) void reduce_kernel(
        float* __restrict__ out, const float* __restrict__ p1) {
    int i = blockIdx.x * 256 + threadIdx.x;   // float4 index, 2M total
    f32x4 a = ((const f32x4*)out)[i];
    f32x4 b = ((const f32x4*)p1)[i];
    ((f32x4*)out)[i] = a + b;
}

extern "C" void kernel_launch(void* const* d_in, const int* in_sizes, int n_in,
                              void* d_out, int out_size, void* d_ws, size_t ws_size,
                              hipStream_t stream) {
    const float* x  = (const float*)d_in[0];
    const float* bw = (const float*)d_in[1];
    const float* sw = (const float*)d_in[2];
    float* out = (float*)d_out;

    // ws layout: Wf [1024 x 9216] bf16 (18.9 MB), Af [8192 x 9216] bf16 (151 MB),
    // part1 [8192 x 1024] fp32 (33.6 MB)
    const size_t nW = (size_t)O_DIM * K_DIM;
    const size_t nA = (size_t)B_DIM * K_DIM;
    ushort_t* Wf = (ushort_t*)d_ws;
    ushort_t* Af = Wf + nW;
    float* part1 = (float*)(Af + nA);
    const size_t need = (nW + nA) * 2 + (size_t)B_DIM * O_DIM * 4;

    const int nsplit = (ws_size >= need) ? 2 : 1;   // ws_size constant -> deterministic
    const int kTiles = (K_DIM / BK) / nsplit;       // 72 or 144
    const int nwg = 128 * nsplit;

    expand_w_kernel<<<(O_DIM * I_DIM / 2) / 256, 256, 0, stream>>>(bw, sw, Wf);
    expand_a_kernel<<<(B_DIM * I_DIM / 2) / 256, 256, 0, stream>>>(x, Af);
    gemm_bt<<<nwg, 512, 0, stream>>>(Af, Wf, out, part1, kTiles);
    if (nsplit == 2)
        reduce_kernel<<<(B_DIM * O_DIM / 4) / 256, 256, 0, stream>>>(out, part1);
}

// Round 9
// 205.127 us; speedup vs baseline: 1.2054x; 1.0379x over previous
//
#include <hip/hip_runtime.h>
#include <hip/hip_bf16.h>

// KAN layer as augmented GEMM:
//   Af[b, c*1024+i] = c==0 ? silu(x[b,i]) : basis_{c-1}(x[b,i])   (bf16)
//   Wf[o, c*1024+i] = c==0 ? base_w[o,i]  : spline_w[o,i,c-1]     (bf16)
//   out = Af @ Wf^T  (fp32 accum via MFMA)
//
// GEMM: 256x256, BK=64, 8 waves 2Mx4N (128x64/wave). ONE barrier + ONE
// vmcnt(0) per K-tile (staged data has >=1-tile lead -> free). Wave-local
// one-phase-ahead pipeline: phase p issues a-frag reads for phase p+1
// (rotating F0/F1/F2 static sets); counted lgkmcnt(4) waits reads issued
// a full MFMA-cluster earlier -> no steady-state LDS stall; waves drift
// between barriers -> cross-wave LDS/MFMA overlap. b[4][2] loaded once
// per tile. A ring-3 + B dbuf = 160KiB. (row&7) swizzle (0-conflict).
// T5 setprio, T1 bijective XCD swizzle, split-K=2 + fp32 reduce.
#define B_DIM 8192
#define I_DIM 1024
#define O_DIM 1024
#define K_DIM 9216   // 9 * 1024

#define BM 256
#define BN 256
#define BK 64

typedef unsigned short ushort_t;
typedef __attribute__((ext_vector_type(8))) short short8;
typedef __attribute__((ext_vector_type(4))) float f32x4;

#define MFMA(a, b, c) __builtin_amdgcn_mfma_f32_16x16x32_bf16((a), (b), (c), 0, 0, 0)

__device__ __forceinline__ ushort_t f2bf(float f) {
    unsigned u = __float_as_uint(f);
    unsigned r = 0x7fffu + ((u >> 16) & 1u);
    return (ushort_t)((u + r) >> 16);
}

__device__ __forceinline__ void llds16(const ushort_t* g, ushort_t* l) {
    __builtin_amdgcn_global_load_lds(
        (const __attribute__((address_space(1))) unsigned int*)g,
        (__attribute__((address_space(3))) unsigned int*)l,
        16, 0, 0);
}

// ---------------- expansion: weights ----------------
__global__ __launch_bounds__(256) void expand_w_kernel(
        const float* __restrict__ bw, const float* __restrict__ sw,
        ushort_t* __restrict__ Wf) {
    int idx = blockIdx.x * 256 + threadIdx.x;   // one thread: (o, 2 consecutive i)
    int o = idx >> 9;
    int i = (idx & 511) << 1;
    ushort_t* out = Wf + (size_t)o * K_DIM + i;
    const float* bp = bw + ((size_t)o << 10) + i;
    *(unsigned*)out = (unsigned)f2bf(bp[0]) | ((unsigned)f2bf(bp[1]) << 16);
    const float* sp = sw + (((size_t)o << 10) + i) * 8;   // 16 contiguous floats
    float v[16];
    #pragma unroll
    for (int n = 0; n < 16; ++n) v[n] = sp[n];
    #pragma unroll
    for (int n = 0; n < 8; ++n)
        *(unsigned*)(out + (size_t)(n + 1) * 1024) =
            (unsigned)f2bf(v[n]) | ((unsigned)f2bf(v[8 + n]) << 16);
}

// ---------------- expansion: activations ----------------
__global__ __launch_bounds__(256) void expand_a_kernel(
        const float* __restrict__ x, ushort_t* __restrict__ Af) {
    int idx = blockIdx.x * 256 + threadIdx.x;   // one thread: (b, 2 consecutive i)
    int b = idx >> 9;
    int i = (idx & 511) << 1;
    const float* xp = x + ((size_t)b << 10) + i;
    float x0 = xp[0], x1 = xp[1];
    ushort_t* out = Af + (size_t)b * K_DIM + i;
    float s0 = x0 / (1.0f + __expf(-x0));
    float s1 = x1 / (1.0f + __expf(-x1));
    *(unsigned*)out = (unsigned)f2bf(s0) | ((unsigned)f2bf(s1) << 16);
    // quadratic B-spline basis, uniform knots -9..9 step 1.8
    float t0 = (x0 + 9.0f) * (1.0f / 1.8f);
    float t1 = (x1 + 9.0f) * (1.0f / 1.8f);
    float fj0 = floorf(t0), fj1 = floorf(t1);
    int j0 = (int)fj0, j1 = (int)fj1;
    float u0 = t0 - fj0, u1 = t1 - fj1;
    float p0 = 0.5f * (1.f - u0) * (1.f - u0);
    float p1 = 0.5f * (-2.f * u0 * u0 + 2.f * u0 + 1.f);
    float p2 = 0.5f * u0 * u0;
    float q0 = 0.5f * (1.f - u1) * (1.f - u1);
    float q1 = 0.5f * (-2.f * u1 * u1 + 2.f * u1 + 1.f);
    float q2 = 0.5f * u1 * u1;
    #pragma unroll
    for (int n = 0; n < 8; ++n) {
        float v0 = (n == j0 - 2) ? p0 : (n == j0 - 1) ? p1 : (n == j0) ? p2 : 0.f;
        float v1 = (n == j1 - 2) ? q0 : (n == j1 - 1) ? q1 : (n == j1) ? q2 : 0.f;
        *(unsigned*)(out + (size_t)(n + 1) * 1024) =
            (unsigned)f2bf(v0) | ((unsigned)f2bf(v1) << 16);
    }
}

// ---------------- GEMM: out[M=8192, N=1024] = Af[M,K] * Wf[N,K]^T ----------------
// grid = 128 * nsplit; wgid = split*128 + bm*4 + bn.
__global__ __launch_bounds__(512) void gemm_bt(
        const ushort_t* __restrict__ Af,
        const ushort_t* __restrict__ Wf,
        float* __restrict__ out, float* __restrict__ part1,
        int kTiles) {
    // A ring-3 (96KB) + B dbuf (64KB) = 160KiB
    __shared__ __align__(16) ushort_t As[3][BM * BK];
    __shared__ __align__(16) ushort_t Bs[2][BN * BK];

    const int tid = threadIdx.x;

    // T1: bijective XCD swizzle (nwg divisible by 8)
    const int nwg = gridDim.x;
    const int orig = blockIdx.x;
    const int wgid = (orig & 7) * (nwg >> 3) + (orig >> 3);
    const int split = wgid >> 7;            // 128 blocks per split
    const int bm = (wgid & 127) >> 2;       // 0..31
    const int bn = wgid & 3;                // 0..3
    const int mBase = bm * BM, nBase = bn * BN;
    const size_t kOff = (size_t)split * kTiles * BK;

    const int lane = tid & 63;
    const int w = tid >> 6;                 // 8 waves: 2M x 4N -> 128x64 per wave
    const int wr = (w >> 2) * 128;
    const int wc = (w & 3) * 64;
    const int fr = lane & 15;
    const int kg = lane >> 4;               // k-group 0..3

    // staging: 512 threads x 16B = 8KB per round = 64 rows of 128B; 4 rounds each.
    // T2 swizzle: 16B slot ^= (row&7); source pre-swizzled, LDS dest linear.
    const int srow = tid >> 3;                                  // 0..63
    const int scolE = (((tid & 7) ^ (srow & 7)) << 3);          // pre-swizzled source col
    const int sdst = (tid & ~63) * 8;                           // wave-uniform elem offset

    auto stageA = [&](int t, int buf) {
        #pragma unroll
        for (int rnd = 0; rnd < 4; ++rnd) {
            const ushort_t* g = Af + (size_t)(mBase + rnd * 64 + srow) * K_DIM
                                   + kOff + (size_t)t * BK + scolE;
            llds16(g, &As[buf][rnd * 4096 + sdst]);
        }
    };
    auto stageB = [&](int t, int buf) {
        #pragma unroll
        for (int rnd = 0; rnd < 4; ++rnd) {
            const ushort_t* g = Wf + (size_t)(nBase + rnd * 64 + srow) * K_DIM
                                   + kOff + (size_t)t * BK + scolE;
            llds16(g, &Bs[buf][rnd * 4096 + sdst]);
        }
    };

    // read-side swizzled 16B-slot offsets: row&7 == fr&7 (wr, wc, 16*m mult of 16)
    const int swz0 = ((kg ^ (fr & 7)) << 3);          // kk = 0
    const int swz1 = (((4 + kg) ^ (fr & 7)) << 3);    // kk = 1

    f32x4 acc[8][4];
    #pragma unroll
    for (int m = 0; m < 8; ++m)
        #pragma unroll
        for (int n = 0; n < 4; ++n) acc[m][n] = (f32x4){0.f, 0.f, 0.f, 0.f};

    short8 b[4][2];          // whole-tile B fragments (resident all 4 phases)
    short8 F0[2][2], F1[2][2], F2[2][2];   // rotating a-frag sets (static names)

    auto ldA = [&](short8 (&F)[2][2], const ushort_t* A_, int m0) {
        #pragma unroll
        for (int i = 0; i < 2; ++i) {
            int arow = (wr + (m0 + i) * 16 + fr) * BK;
            F[i][0] = *(const short8*)&A_[arow + swz0];
            F[i][1] = *(const short8*)&A_[arow + swz1];
        }
    };
    auto mm16 = [&](short8 (&F)[2][2], int p) {   // acc rows 2p..2p+1, all n
        __builtin_amdgcn_s_setprio(1);
        #pragma unroll
        for (int i = 0; i < 2; ++i)
            #pragma unroll
            for (int n = 0; n < 4; ++n) {
                acc[2 * p + i][n] = MFMA(F[i][0], b[n][0], acc[2 * p + i][n]);
                acc[2 * p + i][n] = MFMA(F[i][1], b[n][1], acc[2 * p + i][n]);
            }
        __builtin_amdgcn_s_setprio(0);
    };

    // prologue: B(0)->buf0, A(0)->slot0, A(1)->slot1
    stageB(0, 0);
    stageA(0, 0);
    stageA(1, 1);

    int ca = 0;   // A ring slot holding tile t
    for (int t = 0; t < kTiles; ++t) {
        const ushort_t* A_ = As[ca];
        const ushort_t* B_ = Bs[t & 1];
        const int pa = (ca >= 1) ? ca - 1 : 2;   // slot (ca+2)%3

        // ---- P0 (tile top): drain staged data (>=1-tile lead -> ~free), sync,
        //      issue next stages, issue b(8)+F0(4)+F1(4) reads, wait b+F0. ----
        asm volatile("s_waitcnt vmcnt(0)" ::: "memory");
        __builtin_amdgcn_s_barrier();
        __builtin_amdgcn_sched_barrier(0);
        if (t + 1 < kTiles) stageB(t + 1, (t + 1) & 1);
        if (t + 2 < kTiles) stageA(t + 2, pa);
        #pragma unroll
        for (int n = 0; n < 4; ++n) {
            int brow = (wc + n * 16 + fr) * BK;
            b[n][0] = *(const short8*)&B_[brow + swz0];
            b[n][1] = *(const short8*)&B_[brow + swz1];
        }
        ldA(F0, A_, 0);
        ldA(F1, A_, 2);
        asm volatile("s_waitcnt lgkmcnt(4)" ::: "memory");   // b+F0 done, F1 in flight
        __builtin_amdgcn_sched_barrier(0);
        mm16(F0, 0);

        // ---- P1: issue F2 (a rows 4-5); wait F1 (issued before P0's MFMA) ----
        ldA(F2, A_, 4);
        asm volatile("s_waitcnt lgkmcnt(4)" ::: "memory");
        __builtin_amdgcn_sched_barrier(0);
        mm16(F1, 1);

        // ---- P2: issue F0 (a rows 6-7; F0 consumed 2 phases ago); wait F2 ----
        ldA(F0, A_, 6);
        asm volatile("s_waitcnt lgkmcnt(4)" ::: "memory");
        __builtin_amdgcn_sched_barrier(0);
        mm16(F2, 2);

        // ---- P3: wait F0; pure MFMA (no barrier; waves drift) ----
        asm volatile("s_waitcnt lgkmcnt(0)" ::: "memory");
        __builtin_amdgcn_sched_barrier(0);
        mm16(F0, 3);

        ca = (ca + 1 == 3) ? 0 : ca + 1;
    }

    // epilogue: C/D layout col=lane&15, row=(lane>>4)*4+r
    float* obase = split ? part1 : out;
    const int orow = (lane >> 4) * 4;
    const int ocol = lane & 15;
    #pragma unroll
    for (int m = 0; m < 8; ++m)
        #pragma unroll
        for (int n = 0; n < 4; ++n) {
            size_t base = (size_t)(mBase + wr + m * 16 + orow) * O_DIM
                        + (nBase + wc + n * 16 + ocol);
            #pragma unroll
            for (int r = 0; r < 4; ++r)
                obase[base + (size_t)r * O_DIM] = acc[m][n][r];
        }
}

// ---------------- reduce: out += part1 (float4) ----------------
__global__ __launch_bounds__(256) void reduce_kernel(
        float* __restrict__ out, const float* __restrict__ p1) {
    int i = blockIdx.x * 256 + threadIdx.x;   // float4 index, 2M total
    f32x4 a = ((const f32x4*)out)[i];
    f32x4 b = ((const f32x4*)p1)[i];
    ((f32x4*)out)[i] = a + b;
}

extern "C" void kernel_launch(void* const* d_in, const int* in_sizes, int n_in,
                              void* d_out, int out_size, void* d_ws, size_t ws_size,
                              hipStream_t stream) {
    const float* x  = (const float*)d_in[0];
    const float* bw = (const float*)d_in[1];
    const float* sw = (const float*)d_in[2];
    float* out = (float*)d_out;

    // ws layout: Wf [1024 x 9216] bf16 (18.9 MB), Af [8192 x 9216] bf16 (151 MB),
    // part1 [8192 x 1024] fp32 (33.6 MB)
    const size_t nW = (size_t)O_DIM * K_DIM;
    const size_t nA = (size_t)B_DIM * K_DIM;
    ushort_t* Wf = (ushort_t*)d_ws;
    ushort_t* Af = Wf + nW;
    float* part1 = (float*)(Af + nA);
    const size_t need = (nW + nA) * 2 + (size_t)B_DIM * O_DIM * 4;

    const int nsplit = (ws_size >= need) ? 2 : 1;   // ws_size constant -> deterministic
    const int kTiles = (K_DIM / BK) / nsplit;       // 72 or 144
    const int nwg = 128 * nsplit;

    expand_w_kernel<<<(O_DIM * I_DIM / 2) / 256, 256, 0, stream>>>(bw, sw, Wf);
    expand_a_kernel<<<(B_DIM * I_DIM / 2) / 256, 256, 0, stream>>>(x, Af);
    gemm_bt<<<nwg, 512, 0, stream>>>(Af, Wf, out, part1, kTiles);
    if (nsplit == 2)
        reduce_kernel<<<(B_DIM * O_DIM / 4) / 256, 256, 0, stream>>>(out, part1);
}